// Round 5
// baseline (196.431 us; speedup 1.0000x reference)
//
#include <hip/hip_runtime.h>
#include <hip/hip_bf16.h>

#define N_PTS  4096
#define M_Q    16384
#define C_IN   256
#define C_SKIP 128
#define C_H    384      // C_IN + C_SKIP
#define HDIM   256
#define NSPLIT 32
#define PTS_PER_SPLIT (N_PTS / NSPLIT)   // 128
#define BM     32       // fused kernel rows per block

typedef __bf16 bf16x8 __attribute__((ext_vector_type(8)));
typedef __bf16 bf16x4 __attribute__((ext_vector_type(4)));
typedef float  f32x4  __attribute__((ext_vector_type(4)));

__device__ __forceinline__ __bf16 tobf(float f) {
    __hip_bfloat16 h = __float2bfloat16(f);
    __bf16 r;
    __builtin_memcpy(&r, &h, 2);
    return r;
}

__device__ __forceinline__ void insert3(float d, int j,
                                        float& b0, float& b1, float& b2,
                                        int& i0, int& i1, int& i2) {
    if (d < b2) {
        if (d < b1) {
            b2 = b1; i2 = i1;
            if (d < b0) { b1 = b0; i1 = i0; b0 = d; i0 = j; }
            else        { b1 = d;  i1 = j; }
        } else { b2 = d; i2 = j; }
    }
}

// ---- Phase 0: prep — W1/W2 convert+transpose (n-major), pos4 build ---------
__global__ __launch_bounds__(256) void prep_kernel(
        const float* __restrict__ W1, const float* __restrict__ W2,
        const float* __restrict__ pos,
        __bf16* __restrict__ W1t, __bf16* __restrict__ W2t,
        float4* __restrict__ pos4) {
    const int i = blockIdx.x * 256 + threadIdx.x;
    if (i < C_H * HDIM) {
        const int k = i / HDIM, n = i % HDIM;
        W1t[n * C_H + k] = tobf(W1[i]);
    } else if (i < C_H * HDIM + HDIM * HDIM) {
        const int j = i - C_H * HDIM;
        const int k = j / HDIM, n = j % HDIM;
        W2t[n * HDIM + k] = tobf(W2[j]);
    } else if (i < C_H * HDIM + HDIM * HDIM + N_PTS) {
        const int j = i - (C_H * HDIM + HDIM * HDIM);
        const float px = pos[j*3+0], py = pos[j*3+1], pz = pos[j*3+2];
        pos4[j] = make_float4(px, py, pz, px*px + py*py + pz*pz);
    }
}

// ---- Phase 1: partial kNN, 32-way split (scalar-path point stream) ---------
__global__ __launch_bounds__(256) void knn_part_kernel(
        const float4* __restrict__ pos4, const float* __restrict__ pos_skip,
        float* __restrict__ cand_d, int* __restrict__ cand_i) {
    const int s  = blockIdx.y;
    const int q  = blockIdx.x * 256 + threadIdx.x;
    const int j0 = s * PTS_PER_SPLIT;
    const float m2x = -2.0f * pos_skip[q*3+0];
    const float m2y = -2.0f * pos_skip[q*3+1];
    const float m2z = -2.0f * pos_skip[q*3+2];
    float b0 = 3e38f, b1 = 3e38f, b2 = 3e38f;
    int   i0 = 0, i1 = 0, i2 = 0;
    #pragma unroll 8
    for (int j = 0; j < PTS_PER_SPLIT; ++j) {
        const float4 p = pos4[j0 + j];      // uniform address -> SGPR broadcast
        const float d = fmaf(p.x, m2x, fmaf(p.y, m2y, fmaf(p.z, m2z, p.w)));
        const int  jj = j0 + j;
        const bool c2 = d < b2, c1 = d < b1, c0 = d < b0;
        b2 = c2 ? (c1 ? b1 : d) : b2;  i2 = c2 ? (c1 ? i1 : jj) : i2;
        b1 = c1 ? (c0 ? b0 : d) : b1;  i1 = c1 ? (c0 ? i0 : jj) : i1;
        b0 = c0 ? d : b0;              i0 = c0 ? jj : i0;
    }
    const int base = s * M_Q + q;           // SoA rank-major, coalesced
    cand_d[0*NSPLIT*M_Q + base] = b0;
    cand_d[1*NSPLIT*M_Q + base] = b1;
    cand_d[2*NSPLIT*M_Q + base] = b2;
    cand_i[0*NSPLIT*M_Q + base] = i0;
    cand_i[1*NSPLIT*M_Q + base] = i1;
    cand_i[2*NSPLIT*M_Q + base] = i2;
}

// ---- Phase 2: merge 96 candidates (4 lanes/query) -> top-3 + weights -------
__global__ __launch_bounds__(256) void knn_merge_kernel(
        const float* __restrict__ cand_d, const int* __restrict__ cand_i,
        const float* __restrict__ pos, const float* __restrict__ pos_skip,
        int* __restrict__ idx, float* __restrict__ wn) {
    const int tid = blockIdx.x * 256 + threadIdx.x;
    const int q = tid >> 2;
    const int l = tid & 3;
    float b0 = 3e38f, b1 = 3e38f, b2 = 3e38f;
    int   i0 = 0, i1 = 0, i2 = 0;
    const int SM = NSPLIT * M_Q;
    #pragma unroll
    for (int u = 0; u < NSPLIT/4; ++u) {
        const int s = l * (NSPLIT/4) + u;   // ascending split order, tie-break safe
        const int base = s * M_Q + q;
        const float d0 = cand_d[0*SM + base], d1 = cand_d[1*SM + base], d2c = cand_d[2*SM + base];
        const int   j0 = cand_i[0*SM + base], j1 = cand_i[1*SM + base], j2c = cand_i[2*SM + base];
        insert3(d0, j0,  b0,b1,b2, i0,i1,i2);
        insert3(d1, j1,  b0,b1,b2, i0,i1,i2);
        insert3(d2c, j2c, b0,b1,b2, i0,i1,i2);
    }
    #pragma unroll
    for (int m = 1; m <= 2; m <<= 1) {
        const float nb0 = __shfl_xor(b0, m), nb1 = __shfl_xor(b1, m), nb2 = __shfl_xor(b2, m);
        const int   ni0 = __shfl_xor(i0, m), ni1 = __shfl_xor(i1, m), ni2 = __shfl_xor(i2, m);
        const bool upper = (l & m) != 0;
        float e0 = upper ? b0 : nb0, e1 = upper ? b1 : nb1, e2 = upper ? b2 : nb2;
        int   f0 = upper ? i0 : ni0, f1 = upper ? i1 : ni1, f2 = upper ? i2 : ni2;
        if (upper) { b0 = nb0; b1 = nb1; b2 = nb2; i0 = ni0; i1 = ni1; i2 = ni2; }
        insert3(e0, f0, b0,b1,b2, i0,i1,i2);
        insert3(e1, f1, b0,b1,b2, i0,i1,i2);
        insert3(e2, f2, b0,b1,b2, i0,i1,i2);
    }
    if (l == 0) {
        const float qx = pos_skip[q*3+0], qy = pos_skip[q*3+1], qz = pos_skip[q*3+2];
        float w[3]; int ii[3] = {i0, i1, i2};
        #pragma unroll
        for (int r = 0; r < 3; ++r) {
            const float dx = qx - pos[ii[r]*3+0];
            const float dy = qy - pos[ii[r]*3+1];
            const float dz = qz - pos[ii[r]*3+2];
            const float d2 = dx*dx + dy*dy + dz*dz;   // exact recompute = reference d2k
            w[r] = 1.0f / fmaxf(d2, 1e-16f);
        }
        const float inv = 1.0f / (w[0] + w[1] + w[2]);
        idx[q*3+0] = ii[0]; idx[q*3+1] = ii[1]; idx[q*3+2] = ii[2];
        wn[q*3+0] = w[0]*inv; wn[q*3+1] = w[1]*inv; wn[q*3+2] = w[2]*inv;
    }
}

// ---- Phase 3: fused interp + GEMM1 + ReLU + GEMM2 + bias + tail ------------
// Block: 256 thr (4 waves), BM=32 rows, full N=256.
// Wave w: rows (w&1)*16, n-half (w>>1)*128; 8 n-tiles of 16; K steps of 32.
// LDS: hA[32][392] bf16 (25088 B, overlaid later by hid[32][264] = 16896 B)
//      wB[256][40] bf16 (20480 B).  Total 45568 B -> 2 blocks/CU.
__global__ __launch_bounds__(256) void fused_mlp_kernel(
        const float* __restrict__ x, const float* __restrict__ x_skip,
        const int* __restrict__ idx, const float* __restrict__ wn,
        const __bf16* __restrict__ W1t, const __bf16* __restrict__ W2t,
        const float* __restrict__ b1, const float* __restrict__ b2,
        const float* __restrict__ pos_skip,
        float* __restrict__ out, int out_size) {
    __shared__ __align__(16) char lds[25088 + 20480];
    __bf16 (*hA)[392]   = (__bf16(*)[392])lds;          // rows 784 B (48+1)*16
    __bf16 (*hidS)[264] = (__bf16(*)[264])lds;          // rows 528 B (32+1)*16
    __bf16 (*wB)[40]    = (__bf16(*)[40])(lds + 25088); // rows 80 B

    const int t    = threadIdx.x;
    const int w    = t >> 6;
    const int lane = t & 63;
    const int ln   = lane & 15, kq = lane >> 4;
    const int nh   = w >> 1;          // n-half: 0 or 1 (offset nh*128)
    const int mt   = w & 1;           // m-tile: rows mt*16..mt*16+15
    const int m0   = blockIdx.x * BM;

    // ---- interp: build hA rows (cols 0..255 interp, 256..383 skip) ----
    {
        const int l4 = lane * 4;
        #pragma unroll 2
        for (int j = 0; j < 8; ++j) {
            const int r = w * 8 + j;
            const int m = m0 + r;
            const int   i0 = idx[m*3+0], i1 = idx[m*3+1], i2 = idx[m*3+2];
            const float w0 = wn[m*3+0],  w1 = wn[m*3+1],  w2 = wn[m*3+2];
            const float4 v0 = *(const float4*)(x + (size_t)i0 * C_IN + l4);
            const float4 v1 = *(const float4*)(x + (size_t)i1 * C_IN + l4);
            const float4 v2 = *(const float4*)(x + (size_t)i2 * C_IN + l4);
            bf16x4 o;
            o[0] = tobf(w0*v0.x + w1*v1.x + w2*v2.x);
            o[1] = tobf(w0*v0.y + w1*v1.y + w2*v2.y);
            o[2] = tobf(w0*v0.z + w1*v1.z + w2*v2.z);
            o[3] = tobf(w0*v0.w + w1*v1.w + w2*v2.w);
            *(bf16x4*)&hA[r][l4] = o;
            if (lane < 32) {
                const float4 s = *(const float4*)(x_skip + (size_t)m * C_SKIP + l4);
                bf16x4 os;
                os[0] = tobf(s.x); os[1] = tobf(s.y);
                os[2] = tobf(s.z); os[3] = tobf(s.w);
                *(bf16x4*)&hA[r][C_IN + l4] = os;
            }
        }
    }
    __syncthreads();

    // ---- GEMM1: acc1 = hA[32x384] @ W1t^T, K=384 (12 steps) ----
    f32x4 acc1[8] = {};
    for (int ks = 0; ks < C_H / 32; ++ks) {
        const int k0 = ks * 32;
        int4 wv[4];
        #pragma unroll
        for (int i = 0; i < 4; ++i)
            wv[i] = *(const int4*)(W1t + (size_t)t * C_H + k0 + 8*i);
        __syncthreads();                    // prior wB reads complete
        #pragma unroll
        for (int i = 0; i < 4; ++i)
            *(int4*)&wB[t][8*i] = wv[i];
        __syncthreads();
        const bf16x8 af = *(const bf16x8*)&hA[mt*16 + ln][k0 + kq*8];
        #pragma unroll
        for (int nt = 0; nt < 8; ++nt) {
            const bf16x8 bf = *(const bf16x8*)&wB[nh*128 + nt*16 + ln][kq*8];
            acc1[nt] = __builtin_amdgcn_mfma_f32_16x16x32_bf16(af, bf, acc1[nt], 0, 0, 0);
        }
    }
    __syncthreads();                        // all hA reads done (hid overlays hA)

    // ---- ReLU + bias + bf16, C-layout -> hid LDS (A-layout source) ----
    #pragma unroll
    for (int nt = 0; nt < 8; ++nt) {
        const int n = nh*128 + nt*16 + ln;
        const float bv = b1[n];
        #pragma unroll
        for (int r = 0; r < 4; ++r) {
            float v = acc1[nt][r] + bv;
            v = fmaxf(v, 0.0f);
            hidS[mt*16 + kq*4 + r][n] = tobf(v);
        }
    }

    // ---- GEMM2: acc2 = hid[32x256] @ W2t^T, K=256 (8 steps) ----
    f32x4 acc2[8] = {};
    for (int ks = 0; ks < HDIM / 32; ++ks) {
        const int k0 = ks * 32;
        int4 wv[4];
        #pragma unroll
        for (int i = 0; i < 4; ++i)
            wv[i] = *(const int4*)(W2t + (size_t)t * HDIM + k0 + 8*i);
        __syncthreads();                    // prior wB reads + hid writes visible
        #pragma unroll
        for (int i = 0; i < 4; ++i)
            *(int4*)&wB[t][8*i] = wv[i];
        __syncthreads();
        const bf16x8 af = *(const bf16x8*)&hidS[mt*16 + ln][k0 + kq*8];
        #pragma unroll
        for (int nt = 0; nt < 8; ++nt) {
            const bf16x8 bf = *(const bf16x8*)&wB[nh*128 + nt*16 + ln][kq*8];
            acc2[nt] = __builtin_amdgcn_mfma_f32_16x16x32_bf16(af, bf, acc2[nt], 0, 0, 0);
        }
    }

    // ---- epilogue: + b2 -> out[m][n] ----
    #pragma unroll
    for (int nt = 0; nt < 8; ++nt) {
        const int n = nh*128 + nt*16 + ln;
        const float bv = b2[n];
        #pragma unroll
        for (int r = 0; r < 4; ++r) {
            const int m = m0 + mt*16 + kq*4 + r;
            out[(size_t)m * HDIM + n] = acc2[nt][r] + bv;
        }
    }

    // ---- tail: this block's slice of pos_skip copy + batch zeros ----
    if (t < BM * 3)
        out[(size_t)M_Q * HDIM + m0*3 + t] = pos_skip[m0*3 + t];
    const int zbase = M_Q * HDIM + M_Q * 3;
    const int ztot  = out_size - zbase;
    const int chunk = (ztot + (M_Q/BM) - 1) / (M_Q/BM);
    for (int i = t; i < chunk; i += 256) {
        const int gi = blockIdx.x * chunk + i;
        if (gi < ztot) out[zbase + gi] = 0.0f;
    }
}

extern "C" void kernel_launch(void* const* d_in, const int* in_sizes, int n_in,
                              void* d_out, int out_size, void* d_ws, size_t ws_size,
                              hipStream_t stream) {
    (void)in_sizes; (void)n_in; (void)ws_size;
    const float* x        = (const float*)d_in[0];   // [4096,256]
    const float* pos      = (const float*)d_in[1];   // [4096,3]
    const float* x_skip   = (const float*)d_in[3];   // [16384,128]
    const float* pos_skip = (const float*)d_in[4];   // [16384,3]
    const float* W1       = (const float*)d_in[6];   // [384,256]
    const float* b1       = (const float*)d_in[7];   // [256]
    const float* W2       = (const float*)d_in[8];   // [256,256]
    const float* b2       = (const float*)d_in[9];   // [256]
    float* out = (float*)d_out;

    char* ws = (char*)d_ws;
    float*  cand_d = (float*) (ws);                  // M*96*4 = 6,291,456
    int*    cand_i = (int*)   (ws + 6291456);        // 6,291,456
    int*    idx    = (int*)   (ws + 12582912);       //   196,608
    float*  wn     = (float*) (ws + 12779520);       //   196,608
    __bf16* W1t    = (__bf16*)(ws + 12976128);       //   196,608 (n-major [256][384])
    __bf16* W2t    = (__bf16*)(ws + 13172736);       //   131,072 (n-major [256][256])
    float4* pos4   = (float4*)(ws + 13303808);       //    65,536
                                                     // total ~13.4 MB

    prep_kernel     <<<(C_H*HDIM + HDIM*HDIM + N_PTS + 255)/256, 256, 0, stream>>>(
        W1, W2, pos, W1t, W2t, pos4);
    knn_part_kernel <<<dim3(M_Q/256, NSPLIT), 256, 0, stream>>>(pos4, pos_skip, cand_d, cand_i);
    knn_merge_kernel<<<M_Q*4/256, 256, 0, stream>>>(cand_d, cand_i, pos, pos_skip, idx, wn);
    fused_mlp_kernel<<<M_Q/BM, 256, 0, stream>>>(
        x, x_skip, idx, wn, W1t, W2t, b1, b2, pos_skip, out, out_size);
}

// Round 6
// 167.380 us; speedup vs baseline: 1.1736x; 1.1736x over previous
//
#include <hip/hip_runtime.h>
#include <hip/hip_bf16.h>

#define N_PTS  4096
#define M_Q    16384
#define C_IN   256
#define C_SKIP 128
#define C_H    384      // C_IN + C_SKIP
#define HDIM   256
#define NSPLIT 32
#define PTS_PER_SPLIT (N_PTS / NSPLIT)   // 128

typedef __bf16 bf16x8 __attribute__((ext_vector_type(8)));
typedef __bf16 bf16x4 __attribute__((ext_vector_type(4)));
typedef float  f32x4  __attribute__((ext_vector_type(4)));

__device__ __forceinline__ __bf16 tobf(float f) {
    __hip_bfloat16 h = __float2bfloat16(f);
    __bf16 r;
    __builtin_memcpy(&r, &h, 2);
    return r;
}

__device__ __forceinline__ void insert3(float d, int j,
                                        float& b0, float& b1, float& b2,
                                        int& i0, int& i1, int& i2) {
    if (d < b2) {
        if (d < b1) {
            b2 = b1; i2 = i1;
            if (d < b0) { b1 = b0; i1 = i0; b0 = d; i0 = j; }
            else        { b1 = d;  i1 = j; }
        } else { b2 = d; i2 = j; }
    }
}

// ---- Phase 0: prep — W1/W2 convert+transpose (n-major), pos4 build ---------
__global__ __launch_bounds__(256) void prep_kernel(
        const float* __restrict__ W1, const float* __restrict__ W2,
        const float* __restrict__ pos,
        __bf16* __restrict__ W1t, __bf16* __restrict__ W2t,
        float4* __restrict__ pos4) {
    const int i = blockIdx.x * 256 + threadIdx.x;
    if (i < C_H * HDIM) {
        const int k = i / HDIM, n = i % HDIM;
        W1t[n * C_H + k] = tobf(W1[i]);
    } else if (i < C_H * HDIM + HDIM * HDIM) {
        const int j = i - C_H * HDIM;
        const int k = j / HDIM, n = j % HDIM;
        W2t[n * HDIM + k] = tobf(W2[j]);
    } else if (i < C_H * HDIM + HDIM * HDIM + N_PTS) {
        const int j = i - (C_H * HDIM + HDIM * HDIM);
        const float px = pos[j*3+0], py = pos[j*3+1], pz = pos[j*3+2];
        pos4[j] = make_float4(px, py, pz, px*px + py*py + pz*pz);
    }
}

// ---- Phase 1: partial kNN, 32-way split (scalar-path point stream) ---------
// UNCHANGED from R4 for clean attribution.
__global__ __launch_bounds__(256) void knn_part_kernel(
        const float4* __restrict__ pos4, const float* __restrict__ pos_skip,
        float* __restrict__ cand_d, int* __restrict__ cand_i) {
    const int s  = blockIdx.y;
    const int q  = blockIdx.x * 256 + threadIdx.x;
    const int j0 = s * PTS_PER_SPLIT;
    const float m2x = -2.0f * pos_skip[q*3+0];
    const float m2y = -2.0f * pos_skip[q*3+1];
    const float m2z = -2.0f * pos_skip[q*3+2];
    float b0 = 3e38f, b1 = 3e38f, b2 = 3e38f;
    int   i0 = 0, i1 = 0, i2 = 0;
    #pragma unroll 8
    for (int j = 0; j < PTS_PER_SPLIT; ++j) {
        const float4 p = pos4[j0 + j];      // uniform address -> broadcast load
        const float d = fmaf(p.x, m2x, fmaf(p.y, m2y, fmaf(p.z, m2z, p.w)));
        const int  jj = j0 + j;
        const bool c2 = d < b2, c1 = d < b1, c0 = d < b0;
        b2 = c2 ? (c1 ? b1 : d) : b2;  i2 = c2 ? (c1 ? i1 : jj) : i2;
        b1 = c1 ? (c0 ? b0 : d) : b1;  i1 = c1 ? (c0 ? i0 : jj) : i1;
        b0 = c0 ? d : b0;              i0 = c0 ? jj : i0;
    }
    const int base = s * M_Q + q;           // SoA rank-major, coalesced
    cand_d[0*NSPLIT*M_Q + base] = b0;
    cand_d[1*NSPLIT*M_Q + base] = b1;
    cand_d[2*NSPLIT*M_Q + base] = b2;
    cand_i[0*NSPLIT*M_Q + base] = i0;
    cand_i[1*NSPLIT*M_Q + base] = i1;
    cand_i[2*NSPLIT*M_Q + base] = i2;
}

// ---- Phase 2: fused merge + interp + tail ----------------------------------
// 256 blocks x 256 thr; block owns 64 queries. Merge: 4 lanes/query -> idx/wn
// into LDS. Interp: 64 rows x 96 float4-cols -> h bf16. Tail folded in.
__global__ __launch_bounds__(256) void merge_interp_kernel(
        const float* __restrict__ cand_d, const int* __restrict__ cand_i,
        const float* __restrict__ pos, const float* __restrict__ pos_skip,
        const float* __restrict__ x, const float* __restrict__ x_skip,
        __bf16* __restrict__ h, float* __restrict__ out, int out_size) {
    __shared__ int   sIdx[64][3];
    __shared__ float sW[64][3];
    const int t  = threadIdx.x;
    const int ql = t >> 2, l = t & 3;
    const int m0 = blockIdx.x * 64;
    const int q  = m0 + ql;

    float b0 = 3e38f, b1 = 3e38f, b2 = 3e38f;
    int   i0 = 0, i1 = 0, i2 = 0;
    const int SM = NSPLIT * M_Q;
    #pragma unroll
    for (int u = 0; u < NSPLIT/4; ++u) {
        const int s = l * (NSPLIT/4) + u;   // ascending split order, tie-break safe
        const int base = s * M_Q + q;
        const float d0 = cand_d[0*SM + base], d1 = cand_d[1*SM + base], d2c = cand_d[2*SM + base];
        const int   j0 = cand_i[0*SM + base], j1 = cand_i[1*SM + base], j2c = cand_i[2*SM + base];
        insert3(d0, j0,  b0,b1,b2, i0,i1,i2);
        insert3(d1, j1,  b0,b1,b2, i0,i1,i2);
        insert3(d2c, j2c, b0,b1,b2, i0,i1,i2);
    }
    #pragma unroll
    for (int m = 1; m <= 2; m <<= 1) {
        const float nb0 = __shfl_xor(b0, m), nb1 = __shfl_xor(b1, m), nb2 = __shfl_xor(b2, m);
        const int   ni0 = __shfl_xor(i0, m), ni1 = __shfl_xor(i1, m), ni2 = __shfl_xor(i2, m);
        const bool upper = (l & m) != 0;
        float e0 = upper ? b0 : nb0, e1 = upper ? b1 : nb1, e2 = upper ? b2 : nb2;
        int   f0 = upper ? i0 : ni0, f1 = upper ? i1 : ni1, f2 = upper ? i2 : ni2;
        if (upper) { b0 = nb0; b1 = nb1; b2 = nb2; i0 = ni0; i1 = ni1; i2 = ni2; }
        insert3(e0, f0, b0,b1,b2, i0,i1,i2);
        insert3(e1, f1, b0,b1,b2, i0,i1,i2);
        insert3(e2, f2, b0,b1,b2, i0,i1,i2);
    }
    if (l == 0) {
        const float qx = pos_skip[q*3+0], qy = pos_skip[q*3+1], qz = pos_skip[q*3+2];
        float w[3]; int ii[3] = {i0, i1, i2};
        float wsum = 0.0f;
        #pragma unroll
        for (int r = 0; r < 3; ++r) {
            const float dx = qx - pos[ii[r]*3+0];
            const float dy = qy - pos[ii[r]*3+1];
            const float dz = qz - pos[ii[r]*3+2];
            const float d2 = dx*dx + dy*dy + dz*dz;   // exact recompute = reference d2k
            w[r] = 1.0f / fmaxf(d2, 1e-16f);
            wsum += w[r];
        }
        const float inv = 1.0f / wsum;
        #pragma unroll
        for (int r = 0; r < 3; ++r) { sIdx[ql][r] = ii[r]; sW[ql][r] = w[r] * inv; }
    }
    __syncthreads();

    // interp: 64 rows x 96 float4-cols (cols 0..63 interp, 64..95 skip)
    #pragma unroll 4
    for (int g = 0; g < 24; ++g) {
        const int flat = g * 256 + t;
        const int r  = flat / 96;
        const int c4 = flat % 96;
        const int m  = m0 + r;
        if (c4 < 64) {
            const int c = c4 * 4;
            const int   j0 = sIdx[r][0], j1 = sIdx[r][1], j2 = sIdx[r][2];
            const float w0 = sW[r][0],   w1 = sW[r][1],   w2 = sW[r][2];
            const float4 v0 = *(const float4*)(x + (size_t)j0 * C_IN + c);
            const float4 v1 = *(const float4*)(x + (size_t)j1 * C_IN + c);
            const float4 v2 = *(const float4*)(x + (size_t)j2 * C_IN + c);
            bf16x4 o;
            o[0] = tobf(w0*v0.x + w1*v1.x + w2*v2.x);
            o[1] = tobf(w0*v0.y + w1*v1.y + w2*v2.y);
            o[2] = tobf(w0*v0.z + w1*v1.z + w2*v2.z);
            o[3] = tobf(w0*v0.w + w1*v1.w + w2*v2.w);
            *(bf16x4*)(h + (size_t)m * C_H + c) = o;
        } else {
            const int c = (c4 - 64) * 4;
            const float4 v = *(const float4*)(x_skip + (size_t)m * C_SKIP + c);
            bf16x4 o;
            o[0] = tobf(v.x); o[1] = tobf(v.y); o[2] = tobf(v.z); o[3] = tobf(v.w);
            *(bf16x4*)(h + (size_t)m * C_H + C_IN + c) = o;
        }
    }

    // tail: pos_skip passthrough slice + batch zeros slice
    if (t < 64 * 3)
        out[(size_t)M_Q * HDIM + m0*3 + t] = pos_skip[m0*3 + t];
    const int zbase = M_Q * HDIM + M_Q * 3;
    const int ztot  = out_size - zbase;
    const int chunk = (ztot + 255) / 256;          // 256 blocks
    for (int i2z = t; i2z < chunk; i2z += 256) {
        const int gi = blockIdx.x * chunk + i2z;
        if (gi < ztot) out[zbase + gi] = 0.0f;
    }
}

// ---- Phase 3/4: bf16 MFMA GEMM, double-buffered LDS, reg prefetch ----------
// C[M x 256] = A[M x K] @ Bt^T + bias. A row-major bf16, Bt[256][K] bf16.
// Block 256 thr (4 waves), tile BM=32 x BN=128, BK=32 -> grid (2, M/32)=1024.
// Wave w: m-tile (w&1)*16, n-range (w>>1)*64 (4 n-tiles). One barrier/step.
template<bool RELU, int KDIM, typename OUT_T>
__global__ __launch_bounds__(256) void gemm_bf16_kernel(
        const __bf16* __restrict__ A, const __bf16* __restrict__ Bt,
        const float* __restrict__ bias, OUT_T* __restrict__ C) {
    __shared__ __bf16 As[2][32][40];
    __shared__ __bf16 Bs[2][128][40];
    const int t    = threadIdx.x;
    const int w    = t >> 6;
    const int lane = t & 63;
    const int ln = lane & 15, kq = lane >> 4;
    const int m0 = blockIdx.y * 32;
    const int n0 = blockIdx.x * 128;
    const int wm  = (w & 1) * 16;
    const int wnq = (w >> 1) * 64;

    const int rA = t >> 2, cA = (t & 3) * 8;    // t<128: A 32 rows x 4 thr x 16 B
    const int rB = t >> 1, cB = (t & 1) * 16;   // B 128 rows x 2 thr x 32 B

    constexpr int KS = KDIM / 32;
    int4 ar{}, br0, br1;
    if (t < 128) ar = *(const int4*)(A + (size_t)(m0 + rA) * KDIM + cA);
    br0 = *(const int4*)(Bt + (size_t)(n0 + rB) * KDIM + cB);
    br1 = *(const int4*)(Bt + (size_t)(n0 + rB) * KDIM + cB + 8);

    f32x4 acc[4] = {};

    for (int ks = 0; ks < KS; ++ks) {
        const int p = ks & 1;
        if (t < 128) *(int4*)&As[p][rA][cA] = ar;
        *(int4*)&Bs[p][rB][cB]     = br0;
        *(int4*)&Bs[p][rB][cB + 8] = br1;
        __syncthreads();
        if (ks + 1 < KS) {                      // prefetch next tile, full step early
            const int k0 = (ks + 1) * 32;
            if (t < 128) ar = *(const int4*)(A + (size_t)(m0 + rA) * KDIM + k0 + cA);
            br0 = *(const int4*)(Bt + (size_t)(n0 + rB) * KDIM + k0 + cB);
            br1 = *(const int4*)(Bt + (size_t)(n0 + rB) * KDIM + k0 + cB + 8);
        }
        const bf16x8 af = *(const bf16x8*)&As[p][wm + ln][kq*8];
        #pragma unroll
        for (int nt = 0; nt < 4; ++nt) {
            const bf16x8 bfv = *(const bf16x8*)&Bs[p][wnq + nt*16 + ln][kq*8];
            acc[nt] = __builtin_amdgcn_mfma_f32_16x16x32_bf16(af, bfv, acc[nt], 0, 0, 0);
        }
        // no second barrier: next step writes buffer p^1, never in-flight reads
    }

    #pragma unroll
    for (int nt = 0; nt < 4; ++nt) {
        const int n = n0 + wnq + nt*16 + ln;
        const float bv = bias[n];
        #pragma unroll
        for (int r = 0; r < 4; ++r) {
            const int m = m0 + wm + kq*4 + r;
            float v = acc[nt][r] + bv;
            if (RELU) v = fmaxf(v, 0.0f);
            C[(size_t)m * 256 + n] = (OUT_T)v;
        }
    }
}

extern "C" void kernel_launch(void* const* d_in, const int* in_sizes, int n_in,
                              void* d_out, int out_size, void* d_ws, size_t ws_size,
                              hipStream_t stream) {
    (void)in_sizes; (void)n_in; (void)ws_size;
    const float* x        = (const float*)d_in[0];   // [4096,256]
    const float* pos      = (const float*)d_in[1];   // [4096,3]
    const float* x_skip   = (const float*)d_in[3];   // [16384,128]
    const float* pos_skip = (const float*)d_in[4];   // [16384,3]
    const float* W1       = (const float*)d_in[6];   // [384,256]
    const float* b1       = (const float*)d_in[7];   // [256]
    const float* W2       = (const float*)d_in[8];   // [256,256]
    const float* b2       = (const float*)d_in[9];   // [256]
    float* out = (float*)d_out;

    char* ws = (char*)d_ws;
    float*  cand_d = (float*) (ws);                  // M*96*4 = 6,291,456
    int*    cand_i = (int*)   (ws + 6291456);        // 6,291,456
    __bf16* h      = (__bf16*)(ws + 12582912);       // M*384*2 = 12,582,912
    __bf16* hid    = (__bf16*)(ws + 25165824);       // M*256*2 =  8,388,608
    __bf16* W1t    = (__bf16*)(ws + 33554432);       //   196,608 (n-major [256][384])
    __bf16* W2t    = (__bf16*)(ws + 33751040);       //   131,072 (n-major [256][256])
    float4* pos4   = (float4*)(ws + 33882112);       //    65,536
                                                     // total ~34 MB

    prep_kernel     <<<(C_H*HDIM + HDIM*HDIM + N_PTS + 255)/256, 256, 0, stream>>>(
        W1, W2, pos, W1t, W2t, pos4);
    knn_part_kernel <<<dim3(M_Q/256, NSPLIT), 256, 0, stream>>>(pos4, pos_skip, cand_d, cand_i);
    merge_interp_kernel<<<M_Q/64, 256, 0, stream>>>(
        cand_d, cand_i, pos, pos_skip, x, x_skip, h, out, out_size);
    gemm_bf16_kernel<true, C_H, __bf16><<<dim3(2, M_Q/32), 256, 0, stream>>>(
        h, W1t, b1, (__bf16*)hid);
    gemm_bf16_kernel<false, HDIM, float><<<dim3(2, M_Q/32), 256, 0, stream>>>(
        hid, W2t, b2, out);
}

// Round 7
// 165.945 us; speedup vs baseline: 1.1837x; 1.0086x over previous
//
#include <hip/hip_runtime.h>
#include <hip/hip_bf16.h>

#define N_PTS  4096
#define M_Q    16384
#define C_IN   256
#define C_SKIP 128
#define C_H    384      // C_IN + C_SKIP
#define HDIM   256
#define NSPLIT 32
#define PTS_PER_SPLIT (N_PTS / NSPLIT)   // 128

typedef __bf16 bf16x8 __attribute__((ext_vector_type(8)));
typedef __bf16 bf16x4 __attribute__((ext_vector_type(4)));
typedef float  f32x4  __attribute__((ext_vector_type(4)));

__device__ __forceinline__ __bf16 tobf(float f) {
    __hip_bfloat16 h = __float2bfloat16(f);
    __bf16 r;
    __builtin_memcpy(&r, &h, 2);
    return r;
}

__device__ __forceinline__ void insert3(float d, int j,
                                        float& b0, float& b1, float& b2,
                                        int& i0, int& i1, int& i2) {
    if (d < b2) {
        if (d < b1) {
            b2 = b1; i2 = i1;
            if (d < b0) { b1 = b0; i1 = i0; b0 = d; i0 = j; }
            else        { b1 = d;  i1 = j; }
        } else { b2 = d; i2 = j; }
    }
}

// ---- Phase 0: prep — W1/W2 convert+transpose (n-major), pos4 build ---------
__global__ __launch_bounds__(256) void prep_kernel(
        const float* __restrict__ W1, const float* __restrict__ W2,
        const float* __restrict__ pos,
        __bf16* __restrict__ W1t, __bf16* __restrict__ W2t,
        float4* __restrict__ pos4) {
    const int i = blockIdx.x * 256 + threadIdx.x;
    if (i < C_H * HDIM) {
        const int k = i / HDIM, n = i % HDIM;
        W1t[n * C_H + k] = tobf(W1[i]);
    } else if (i < C_H * HDIM + HDIM * HDIM) {
        const int j = i - C_H * HDIM;
        const int k = j / HDIM, n = j % HDIM;
        W2t[n * HDIM + k] = tobf(W2[j]);
    } else if (i < C_H * HDIM + HDIM * HDIM + N_PTS) {
        const int j = i - (C_H * HDIM + HDIM * HDIM);
        const float px = pos[j*3+0], py = pos[j*3+1], pz = pos[j*3+2];
        pos4[j] = make_float4(px, py, pz, px*px + py*py + pz*pz);
    }
}

// ---- Phase 1: partial kNN, 32-way split, 2 queries/thread ------------------
// Point stream via wave-uniform broadcast loads (no LDS — R3 lesson).
// Two independent top-3 chains per thread hide the cndmask dep-chain latency.
__global__ __launch_bounds__(256) void knn_part_kernel(
        const float4* __restrict__ pos4, const float* __restrict__ pos_skip,
        float* __restrict__ cand_d, int* __restrict__ cand_i) {
    const int s  = blockIdx.y;
    const int qa = blockIdx.x * 512 + threadIdx.x;
    const int qb = qa + 256;
    const int j0 = s * PTS_PER_SPLIT;
    const float ax = -2.0f * pos_skip[qa*3+0];
    const float ay = -2.0f * pos_skip[qa*3+1];
    const float az = -2.0f * pos_skip[qa*3+2];
    const float bx = -2.0f * pos_skip[qb*3+0];
    const float by = -2.0f * pos_skip[qb*3+1];
    const float bz = -2.0f * pos_skip[qb*3+2];
    float A0 = 3e38f, A1 = 3e38f, A2 = 3e38f;
    float B0 = 3e38f, B1 = 3e38f, B2 = 3e38f;
    int   ia0 = 0, ia1 = 0, ia2 = 0, ib0 = 0, ib1 = 0, ib2 = 0;
    #pragma unroll 8
    for (int j = 0; j < PTS_PER_SPLIT; ++j) {
        const float4 p = pos4[j0 + j];      // uniform address -> broadcast load
        const float dA = fmaf(p.x, ax, fmaf(p.y, ay, fmaf(p.z, az, p.w)));
        const float dB = fmaf(p.x, bx, fmaf(p.y, by, fmaf(p.z, bz, p.w)));
        const int  jj = j0 + j;
        {
            const bool c2 = dA < A2, c1 = dA < A1, c0 = dA < A0;
            A2 = c2 ? (c1 ? A1 : dA) : A2;  ia2 = c2 ? (c1 ? ia1 : jj) : ia2;
            A1 = c1 ? (c0 ? A0 : dA) : A1;  ia1 = c1 ? (c0 ? ia0 : jj) : ia1;
            A0 = c0 ? dA : A0;              ia0 = c0 ? jj : ia0;
        }
        {
            const bool c2 = dB < B2, c1 = dB < B1, c0 = dB < B0;
            B2 = c2 ? (c1 ? B1 : dB) : B2;  ib2 = c2 ? (c1 ? ib1 : jj) : ib2;
            B1 = c1 ? (c0 ? B0 : dB) : B1;  ib1 = c1 ? (c0 ? ib0 : jj) : ib1;
            B0 = c0 ? dB : B0;              ib0 = c0 ? jj : ib0;
        }
    }
    const int SM = NSPLIT * M_Q;
    const int basea = s * M_Q + qa;         // SoA rank-major, coalesced
    const int baseb = s * M_Q + qb;
    cand_d[0*SM + basea] = A0;  cand_d[0*SM + baseb] = B0;
    cand_d[1*SM + basea] = A1;  cand_d[1*SM + baseb] = B1;
    cand_d[2*SM + basea] = A2;  cand_d[2*SM + baseb] = B2;
    cand_i[0*SM + basea] = ia0; cand_i[0*SM + baseb] = ib0;
    cand_i[1*SM + basea] = ia1; cand_i[1*SM + baseb] = ib1;
    cand_i[2*SM + basea] = ia2; cand_i[2*SM + baseb] = ib2;
}

// ---- Phase 2: fused merge + interp + tail (unchanged from R6) --------------
__global__ __launch_bounds__(256) void merge_interp_kernel(
        const float* __restrict__ cand_d, const int* __restrict__ cand_i,
        const float* __restrict__ pos, const float* __restrict__ pos_skip,
        const float* __restrict__ x, const float* __restrict__ x_skip,
        __bf16* __restrict__ h, float* __restrict__ out, int out_size) {
    __shared__ int   sIdx[64][3];
    __shared__ float sW[64][3];
    const int t  = threadIdx.x;
    const int ql = t >> 2, l = t & 3;
    const int m0 = blockIdx.x * 64;
    const int q  = m0 + ql;

    float b0 = 3e38f, b1 = 3e38f, b2 = 3e38f;
    int   i0 = 0, i1 = 0, i2 = 0;
    const int SM = NSPLIT * M_Q;
    #pragma unroll
    for (int u = 0; u < NSPLIT/4; ++u) {
        const int s = l * (NSPLIT/4) + u;   // ascending split order, tie-break safe
        const int base = s * M_Q + q;
        const float d0 = cand_d[0*SM + base], d1 = cand_d[1*SM + base], d2c = cand_d[2*SM + base];
        const int   j0 = cand_i[0*SM + base], j1 = cand_i[1*SM + base], j2c = cand_i[2*SM + base];
        insert3(d0, j0,  b0,b1,b2, i0,i1,i2);
        insert3(d1, j1,  b0,b1,b2, i0,i1,i2);
        insert3(d2c, j2c, b0,b1,b2, i0,i1,i2);
    }
    #pragma unroll
    for (int m = 1; m <= 2; m <<= 1) {
        const float nb0 = __shfl_xor(b0, m), nb1 = __shfl_xor(b1, m), nb2 = __shfl_xor(b2, m);
        const int   ni0 = __shfl_xor(i0, m), ni1 = __shfl_xor(i1, m), ni2 = __shfl_xor(i2, m);
        const bool upper = (l & m) != 0;
        float e0 = upper ? b0 : nb0, e1 = upper ? b1 : nb1, e2 = upper ? b2 : nb2;
        int   f0 = upper ? i0 : ni0, f1 = upper ? i1 : ni1, f2 = upper ? i2 : ni2;
        if (upper) { b0 = nb0; b1 = nb1; b2 = nb2; i0 = ni0; i1 = ni1; i2 = ni2; }
        insert3(e0, f0, b0,b1,b2, i0,i1,i2);
        insert3(e1, f1, b0,b1,b2, i0,i1,i2);
        insert3(e2, f2, b0,b1,b2, i0,i1,i2);
    }
    if (l == 0) {
        const float qx = pos_skip[q*3+0], qy = pos_skip[q*3+1], qz = pos_skip[q*3+2];
        float w[3]; int ii[3] = {i0, i1, i2};
        float wsum = 0.0f;
        #pragma unroll
        for (int r = 0; r < 3; ++r) {
            const float dx = qx - pos[ii[r]*3+0];
            const float dy = qy - pos[ii[r]*3+1];
            const float dz = qz - pos[ii[r]*3+2];
            const float d2 = dx*dx + dy*dy + dz*dz;   // exact recompute = reference d2k
            w[r] = 1.0f / fmaxf(d2, 1e-16f);
            wsum += w[r];
        }
        const float inv = 1.0f / wsum;
        #pragma unroll
        for (int r = 0; r < 3; ++r) { sIdx[ql][r] = ii[r]; sW[ql][r] = w[r] * inv; }
    }
    __syncthreads();

    // interp: 64 rows x 96 float4-cols (cols 0..63 interp, 64..95 skip)
    #pragma unroll 4
    for (int g = 0; g < 24; ++g) {
        const int flat = g * 256 + t;
        const int r  = flat / 96;
        const int c4 = flat % 96;
        const int m  = m0 + r;
        if (c4 < 64) {
            const int c = c4 * 4;
            const int   j0 = sIdx[r][0], j1 = sIdx[r][1], j2 = sIdx[r][2];
            const float w0 = sW[r][0],   w1 = sW[r][1],   w2 = sW[r][2];
            const float4 v0 = *(const float4*)(x + (size_t)j0 * C_IN + c);
            const float4 v1 = *(const float4*)(x + (size_t)j1 * C_IN + c);
            const float4 v2 = *(const float4*)(x + (size_t)j2 * C_IN + c);
            bf16x4 o;
            o[0] = tobf(w0*v0.x + w1*v1.x + w2*v2.x);
            o[1] = tobf(w0*v0.y + w1*v1.y + w2*v2.y);
            o[2] = tobf(w0*v0.z + w1*v1.z + w2*v2.z);
            o[3] = tobf(w0*v0.w + w1*v1.w + w2*v2.w);
            *(bf16x4*)(h + (size_t)m * C_H + c) = o;
        } else {
            const int c = (c4 - 64) * 4;
            const float4 v = *(const float4*)(x_skip + (size_t)m * C_SKIP + c);
            bf16x4 o;
            o[0] = tobf(v.x); o[1] = tobf(v.y); o[2] = tobf(v.z); o[3] = tobf(v.w);
            *(bf16x4*)(h + (size_t)m * C_H + C_IN + c) = o;
        }
    }

    // tail: pos_skip passthrough slice + batch zeros slice
    if (t < 64 * 3)
        out[(size_t)M_Q * HDIM + m0*3 + t] = pos_skip[m0*3 + t];
    const int zbase = M_Q * HDIM + M_Q * 3;
    const int ztot  = out_size - zbase;
    const int chunk = (ztot + 255) / 256;          // 256 blocks
    for (int i2z = t; i2z < chunk; i2z += 256) {
        const int gi = blockIdx.x * chunk + i2z;
        if (gi < ztot) out[zbase + gi] = 0.0f;
    }
}

// ---- Phase 3/4: bf16 MFMA GEMM — R4 tile shape + single-barrier dbuf -------
// C[M x 256] = A[M x K] @ Bt^T + bias. A row-major bf16, Bt[256][K] bf16.
// Block 256 thr (4 waves), BM=64 x BN=128, BK=32 -> grid (2, M/64) = 512.
// Wave w: rows (w>>1)*32 (2 m-tiles), cols (w&1)*64 (4 n-tiles): 8 MFMA/step.
template<bool RELU, int KDIM, typename OUT_T>
__global__ __launch_bounds__(256) void gemm_bf16_kernel(
        const __bf16* __restrict__ A, const __bf16* __restrict__ Bt,
        const float* __restrict__ bias, OUT_T* __restrict__ C) {
    __shared__ __bf16 As[2][64][40];    // 40-elem rows: +16B pad
    __shared__ __bf16 Bs[2][128][40];
    const int t    = threadIdx.x;
    const int w    = t >> 6;
    const int lane = t & 63;
    const int ln = lane & 15, kq = lane >> 4;
    const int m0 = blockIdx.y * 64;
    const int n0 = blockIdx.x * 128;
    const int wm = (w >> 1) * 32;
    const int wn = (w & 1) * 64;

    const int rA = t >> 1, cA = (t & 1) * 16;   // A: t<128, 64 rows x 2 thr x 16 el
                                                // B: all t, 128 rows x 2 thr x 16 el
    constexpr int KS = KDIM / 32;
    int4 a0{}, a1{}, b0v, b1v;
    if (t < 128) {
        a0 = *(const int4*)(A + (size_t)(m0 + rA) * KDIM + cA);
        a1 = *(const int4*)(A + (size_t)(m0 + rA) * KDIM + cA + 8);
    }
    b0v = *(const int4*)(Bt + (size_t)(n0 + rA) * KDIM + cA);
    b1v = *(const int4*)(Bt + (size_t)(n0 + rA) * KDIM + cA + 8);

    f32x4 acc[2][4] = {};

    for (int ks = 0; ks < KS; ++ks) {
        const int p = ks & 1;
        if (t < 128) {
            *(int4*)&As[p][rA][cA]     = a0;
            *(int4*)&As[p][rA][cA + 8] = a1;
        }
        *(int4*)&Bs[p][rA][cA]     = b0v;
        *(int4*)&Bs[p][rA][cA + 8] = b1v;
        __syncthreads();
        if (ks + 1 < KS) {                      // prefetch next tile a step early
            const int k0 = (ks + 1) * 32;
            if (t < 128) {
                a0 = *(const int4*)(A + (size_t)(m0 + rA) * KDIM + k0 + cA);
                a1 = *(const int4*)(A + (size_t)(m0 + rA) * KDIM + k0 + cA + 8);
            }
            b0v = *(const int4*)(Bt + (size_t)(n0 + rA) * KDIM + k0 + cA);
            b1v = *(const int4*)(Bt + (size_t)(n0 + rA) * KDIM + k0 + cA + 8);
        }
        bf16x8 af[2], bfv[4];
        #pragma unroll
        for (int mt = 0; mt < 2; ++mt)
            af[mt] = *(const bf16x8*)&As[p][wm + mt*16 + ln][kq*8];
        #pragma unroll
        for (int nt = 0; nt < 4; ++nt)
            bfv[nt] = *(const bf16x8*)&Bs[p][wn + nt*16 + ln][kq*8];
        #pragma unroll
        for (int mt = 0; mt < 2; ++mt)
            #pragma unroll
            for (int nt = 0; nt < 4; ++nt)
                acc[mt][nt] = __builtin_amdgcn_mfma_f32_16x16x32_bf16(
                                  af[mt], bfv[nt], acc[mt][nt], 0, 0, 0);
        // single barrier per step: next write targets buffer p^1, whose last
        // reads (step ks-1) completed before this step's barrier.
    }

    // epilogue: C/D layout col=lane&15, row=(lane>>4)*4+reg
    #pragma unroll
    for (int nt = 0; nt < 4; ++nt) {
        const int n = n0 + wn + nt*16 + ln;
        const float bv = bias[n];
        #pragma unroll
        for (int mt = 0; mt < 2; ++mt) {
            const int mbase = m0 + wm + mt*16 + kq*4;
            #pragma unroll
            for (int r = 0; r < 4; ++r) {
                float v = acc[mt][nt][r] + bv;
                if (RELU) v = fmaxf(v, 0.0f);
                C[(size_t)(mbase + r) * 256 + n] = (OUT_T)v;
            }
        }
    }
}

extern "C" void kernel_launch(void* const* d_in, const int* in_sizes, int n_in,
                              void* d_out, int out_size, void* d_ws, size_t ws_size,
                              hipStream_t stream) {
    (void)in_sizes; (void)n_in; (void)ws_size;
    const float* x        = (const float*)d_in[0];   // [4096,256]
    const float* pos      = (const float*)d_in[1];   // [4096,3]
    const float* x_skip   = (const float*)d_in[3];   // [16384,128]
    const float* pos_skip = (const float*)d_in[4];   // [16384,3]
    const float* W1       = (const float*)d_in[6];   // [384,256]
    const float* b1       = (const float*)d_in[7];   // [256]
    const float* W2       = (const float*)d_in[8];   // [256,256]
    const float* b2       = (const float*)d_in[9];   // [256]
    float* out = (float*)d_out;

    char* ws = (char*)d_ws;
    float*  cand_d = (float*) (ws);                  // M*96*4 = 6,291,456
    int*    cand_i = (int*)   (ws + 6291456);        // 6,291,456
    __bf16* h      = (__bf16*)(ws + 12582912);       // M*384*2 = 12,582,912
    __bf16* hid    = (__bf16*)(ws + 25165824);       // M*256*2 =  8,388,608
    __bf16* W1t    = (__bf16*)(ws + 33554432);       //   196,608 (n-major [256][384])
    __bf16* W2t    = (__bf16*)(ws + 33751040);       //   131,072 (n-major [256][256])
    float4* pos4   = (float4*)(ws + 33882112);       //    65,536
                                                     // total ~34 MB

    prep_kernel     <<<(C_H*HDIM + HDIM*HDIM + N_PTS + 255)/256, 256, 0, stream>>>(
        W1, W2, pos, W1t, W2t, pos4);
    knn_part_kernel <<<dim3(M_Q/512, NSPLIT), 256, 0, stream>>>(pos4, pos_skip, cand_d, cand_i);
    merge_interp_kernel<<<M_Q/64, 256, 0, stream>>>(
        cand_d, cand_i, pos, pos_skip, x, x_skip, h, out, out_size);
    gemm_bf16_kernel<true, C_H, __bf16><<<dim3(2, M_Q/64), 256, 0, stream>>>(
        h, W1t, b1, (__bf16*)hid);
    gemm_bf16_kernel<false, HDIM, float><<<dim3(2, M_Q/64), 256, 0, stream>>>(
        hid, W2t, b2, out);
}